// Round 1
// baseline (581.811 us; speedup 1.0000x reference)
//
#include <hip/hip_runtime.h>

// SwinV2 window attention, MI355X. Pipeline:
//   prep: cast qkv_w/proj_w -> bf16, build CPB table, cast x -> bf16
//   k_gemm_bt<false>: qkv = x @ qkv_w^T + b   (bf16 MFMA, bf16 out)
//   k_attn: per (window,head) cosine attention (MFMA 16x16x32, pad 49->64)
//   k_gemm_bt<true>:  out = y @ proj_w^T + b  (f32 out)
//
// Workspace layout (bytes):
//   0          x_bf      77,070,336
//   77070336   qkvw_bf      884,736
//   77955072   projw_bf     294,912
//   78249984   cpb_t        115,248 (padded to 115,712)
//   78365696   qkv_bf   231,211,008
//   309576704  y_bf      77,070,336
//   total ~369 MB

typedef float f32x4 __attribute__((ext_vector_type(4)));
typedef __bf16 bf16x8 __attribute__((ext_vector_type(8)));
typedef unsigned short u16;
typedef u16 u16x8 __attribute__((ext_vector_type(8)));

__device__ __forceinline__ float b2f(unsigned u) {  // u: bf16 bits in low 16
  return __builtin_bit_cast(float, u << 16);
}
__device__ __forceinline__ u16 f2b(float f) {  // RNE f32->bf16
  unsigned u = __builtin_bit_cast(unsigned, f);
  u += 0x7fffu + ((u >> 16) & 1u);
  return (u16)(u >> 16);
}

#define GLD16(gp, lp)                                        \
  __builtin_amdgcn_global_load_lds(                          \
      (const __attribute__((address_space(1))) void*)(gp),   \
      (__attribute__((address_space(3))) void*)(lp), 16, 0, 0)

// ---------------- cast f32 -> bf16, 8 elems/thread ----------------
__global__ __launch_bounds__(256) void k_cast(const float* __restrict__ in,
                                              u16* __restrict__ out, int n8) {
  int i = blockIdx.x * 256 + threadIdx.x;
  if (i >= n8) return;
  const float4* p = reinterpret_cast<const float4*>(in) + (size_t)i * 2;
  float4 a = p[0], b = p[1];
  u16x8 r;
  r[0] = f2b(a.x); r[1] = f2b(a.y); r[2] = f2b(a.z); r[3] = f2b(a.w);
  r[4] = f2b(b.x); r[5] = f2b(b.y); r[6] = f2b(b.z); r[7] = f2b(b.w);
  *(reinterpret_cast<u16x8*>(out) + i) = r;
}

// ---------------- CPB bias table: cpb_t[h][n][m] ----------------
__global__ __launch_bounds__(64) void k_cpb(const float* __restrict__ w1,
                                            const float* __restrict__ b1,
                                            const float* __restrict__ w2,
                                            const float* __restrict__ b2,
                                            float* __restrict__ cpb_t) {
  int p = blockIdx.x * 64 + threadIdx.x;
  if (p >= 49 * 49) return;
  int n = p / 49, m = p % 49;
  float d0 = (float)(n / 7 - m / 7);
  float d1 = (float)(n % 7 - m % 7);
  float a0 = log1pf(fabsf(d0)); a0 = (d0 < 0.f) ? -a0 : a0;
  float a1 = log1pf(fabsf(d1)); a1 = (d1 < 0.f) ? -a1 : a1;
  float acc[12];
#pragma unroll
  for (int h = 0; h < 12; ++h) acc[h] = b2[h];
  for (int j = 0; j < 64; ++j) {
    float hj = fmaxf(a0 * w1[2 * j] + a1 * w1[2 * j + 1] + b1[j], 0.f);
#pragma unroll
    for (int h = 0; h < 12; ++h) acc[h] += hj * w2[h * 64 + j];
  }
#pragma unroll
  for (int h = 0; h < 12; ++h) cpb_t[h * 2401 + p] = acc[h];
}

// ---------------- GEMM: C[M,N] = A[M,K] @ W[N,K]^T + bias ----------------
// 128x128 tile, BK=32, 4 waves (2x2), each wave 64x64 (4x4 MFMA tiles).
// LDS staged via global_load_lds width 16, double-buffered, 1 barrier/step.
template <bool OUT_F32>
__global__ __launch_bounds__(256) void k_gemm_bt(
    const u16* __restrict__ A, const u16* __restrict__ W,
    const float* __restrict__ bias, void* __restrict__ Cv,
    int M, int N, int K) {
  (void)M;
  __shared__ __align__(16) u16 sA[2][4096];  // [128][32]
  __shared__ __align__(16) u16 sB[2][4096];
  const int tid = threadIdx.x;
  const int nt = N >> 7;
  const int m0 = (blockIdx.x / nt) << 7;
  const int n0 = (blockIdx.x % nt) << 7;
  const int srow = tid >> 2;           // 0..63
  const int scol = (tid & 3) << 3;     // 0,8,16,24
  const u16* ga0 = A + (size_t)(m0 + srow) * K + scol;
  const u16* ga1 = ga0 + (size_t)64 * K;
  const u16* gw0 = W + (size_t)(n0 + srow) * K + scol;
  const u16* gw1 = gw0 + (size_t)64 * K;
  const int KT = K >> 5;

#define STAGE(buf, kk)                              \
  do {                                              \
    GLD16(ga0 + (kk), &sA[buf][tid * 8]);           \
    GLD16(ga1 + (kk), &sA[buf][2048 + tid * 8]);    \
    GLD16(gw0 + (kk), &sB[buf][tid * 8]);           \
    GLD16(gw1 + (kk), &sB[buf][2048 + tid * 8]);    \
  } while (0)

  STAGE(0, 0);

  const f32x4 z4 = {0.f, 0.f, 0.f, 0.f};
  f32x4 acc[4][4];
#pragma unroll
  for (int i = 0; i < 4; ++i)
#pragma unroll
    for (int j = 0; j < 4; ++j) acc[i][j] = z4;

  const int l = tid & 63, w = tid >> 6;
  const int wm = (w >> 1) << 6, wn = (w & 1) << 6;
  const int lr = l & 15, lg = l >> 4;
  const int arow = wm + lr, brow = wn + lr;

  for (int t = 0; t < KT; ++t) {
    __syncthreads();  // drains vmcnt: tile t resident in sA/sB[t&1]
    if (t + 1 < KT) STAGE((t + 1) & 1, (t + 1) * 32);
    const u16* pa = sA[t & 1];
    const u16* pb = sB[t & 1];
    bf16x8 af[4], bfv[4];
#pragma unroll
    for (int mi = 0; mi < 4; ++mi)
      af[mi] = __builtin_bit_cast(bf16x8,
          *reinterpret_cast<const u16x8*>(pa + (arow + mi * 16) * 32 + lg * 8));
#pragma unroll
    for (int ni = 0; ni < 4; ++ni)
      bfv[ni] = __builtin_bit_cast(bf16x8,
          *reinterpret_cast<const u16x8*>(pb + (brow + ni * 16) * 32 + lg * 8));
#pragma unroll
    for (int mi = 0; mi < 4; ++mi)
#pragma unroll
      for (int ni = 0; ni < 4; ++ni)
        acc[mi][ni] = __builtin_amdgcn_mfma_f32_16x16x32_bf16(
            af[mi], bfv[ni], acc[mi][ni], 0, 0, 0);
  }
#undef STAGE

  float bv[4];
#pragma unroll
  for (int ni = 0; ni < 4; ++ni) bv[ni] = bias[n0 + wn + ni * 16 + lr];
#pragma unroll
  for (int mi = 0; mi < 4; ++mi)
#pragma unroll
    for (int r = 0; r < 4; ++r) {
      const size_t row = (size_t)(m0 + wm + mi * 16 + lg * 4 + r);
#pragma unroll
      for (int ni = 0; ni < 4; ++ni) {
        const int col = n0 + wn + ni * 16 + lr;
        float v = acc[mi][ni][r] + bv[ni];
        if (OUT_F32)
          reinterpret_cast<float*>(Cv)[row * N + col] = v;
        else
          reinterpret_cast<u16*>(Cv)[row * N + col] = f2b(v);
      }
    }
}

// ---------------- attention: one wave per (window b, head h) ----------------
__global__ __launch_bounds__(64) void k_attn(
    const u16* __restrict__ qkv, const float* __restrict__ tau,
    const float* __restrict__ cpb_t, const float* __restrict__ mask,
    u16* __restrict__ y) {
  const int b = blockIdx.x, h = blockIdx.y;
  const int l = threadIdx.x;
  // lq/lk: [64][40] bf16 (5120 B each); vt: [32][72]; lp overlays lq+lk.
  __shared__ __align__(16) char smem[14848];
  u16(*lq)[40] = reinterpret_cast<u16(*)[40]>(smem);
  u16(*lk)[40] = reinterpret_cast<u16(*)[40]>(smem + 5120);
  u16(*vt)[72] = reinterpret_cast<u16(*)[72]>(smem + 10240);
  u16(*lp)[72] = reinterpret_cast<u16(*)[72]>(smem);  // reused after S

  const float tauh = fmaxf(tau[h], 0.01f);
  const bool valid = l < 49;
  {
    const int row = valid ? l : 0;
    const u16* base = qkv + ((size_t)b * 49 + row) * 1152 + h * 32;
    u16x8 v8s[4];
    float qv[32], kv[32];
#pragma unroll
    for (int c = 0; c < 4; ++c) {
      u16x8 q8 = {0, 0, 0, 0, 0, 0, 0, 0};
      u16x8 k8 = {0, 0, 0, 0, 0, 0, 0, 0};
      u16x8 v8 = {0, 0, 0, 0, 0, 0, 0, 0};
      if (valid) {
        q8 = *reinterpret_cast<const u16x8*>(base + c * 8);
        k8 = *reinterpret_cast<const u16x8*>(base + 384 + c * 8);
        v8 = *reinterpret_cast<const u16x8*>(base + 768 + c * 8);
      }
      v8s[c] = v8;
#pragma unroll
      for (int e = 0; e < 8; ++e) {
        qv[c * 8 + e] = b2f((unsigned)q8[e]);
        kv[c * 8 + e] = b2f((unsigned)k8[e]);
      }
    }
    float sq = 0.f, sk = 0.f;
#pragma unroll
    for (int j = 0; j < 32; ++j) { sq += qv[j] * qv[j]; sk += kv[j] * kv[j]; }
    const float qs = (1.f / fmaxf(sqrtf(sq), 1e-12f)) / tauh;  // fold 1/tau
    const float ks = 1.f / fmaxf(sqrtf(sk), 1e-12f);
#pragma unroll
    for (int c = 0; c < 4; ++c) {
      u16x8 wq, wk;
#pragma unroll
      for (int e = 0; e < 8; ++e) {
        wq[e] = f2b(qv[c * 8 + e] * qs);
        wk[e] = f2b(kv[c * 8 + e] * ks);
      }
      *reinterpret_cast<u16x8*>(&lq[l][c * 8]) = wq;
      *reinterpret_cast<u16x8*>(&lk[l][c * 8]) = wk;
    }
    // V transposed: vt[d][m]; padded cols m>=49 are zeroed by lanes 49..63
#pragma unroll
    for (int c = 0; c < 4; ++c)
#pragma unroll
      for (int e = 0; e < 8; ++e) vt[c * 8 + e][l] = v8s[c][e];
  }
  __syncthreads();

  const int lr = l & 15, lg = l >> 4;
  bf16x8 aq[4], bk[4];
#pragma unroll
  for (int i = 0; i < 4; ++i) {
    aq[i] = __builtin_bit_cast(bf16x8,
        *reinterpret_cast<const u16x8*>(&lq[i * 16 + lr][lg * 8]));
    bk[i] = __builtin_bit_cast(bf16x8,
        *reinterpret_cast<const u16x8*>(&lk[i * 16 + lr][lg * 8]));
  }
  const f32x4 z4 = {0.f, 0.f, 0.f, 0.f};
  f32x4 s[4][4];
#pragma unroll
  for (int i = 0; i < 4; ++i)
#pragma unroll
    for (int j = 0; j < 4; ++j) s[i][j] = z4;
#pragma unroll
  for (int mi = 0; mi < 4; ++mi)
#pragma unroll
    for (int ni = 0; ni < 4; ++ni)
      s[mi][ni] = __builtin_amdgcn_mfma_f32_16x16x32_bf16(aq[mi], bk[ni],
                                                          s[mi][ni], 0, 0, 0);

  // bias + mask + masked softmax (C/D map: col=lane&15, row=(lane>>4)*4+reg)
  const float* cpbh = cpb_t + h * 2401;
  const float* mw = mask + (size_t)(b & 63) * 2401;
  float rs[4][4];
#pragma unroll
  for (int mi = 0; mi < 4; ++mi) {
#pragma unroll
    for (int r = 0; r < 4; ++r) {
      const int n = mi * 16 + lg * 4 + r;
      float sv[4];
#pragma unroll
      for (int ni = 0; ni < 4; ++ni) {
        const int m = ni * 16 + lr;
        float v = s[mi][ni][r];
        if (n < 49 && m < 49) v += cpbh[n * 49 + m] + mw[n * 49 + m];
        else v = -1e30f;
        sv[ni] = v;
      }
      float mx = fmaxf(fmaxf(sv[0], sv[1]), fmaxf(sv[2], sv[3]));
      mx = fmaxf(mx, __shfl_xor(mx, 1));
      mx = fmaxf(mx, __shfl_xor(mx, 2));
      mx = fmaxf(mx, __shfl_xor(mx, 4));
      mx = fmaxf(mx, __shfl_xor(mx, 8));
      float sum = 0.f;
#pragma unroll
      for (int ni = 0; ni < 4; ++ni) {
        float pv = __expf(sv[ni] - mx);
        s[mi][ni][r] = pv;  // unnormalized; O scaled by 1/sum at the end
        sum += pv;
      }
      sum += __shfl_xor(sum, 1);
      sum += __shfl_xor(sum, 2);
      sum += __shfl_xor(sum, 4);
      sum += __shfl_xor(sum, 8);
      rs[mi][r] = 1.f / sum;
    }
  }
  __syncthreads();  // lq/lk dead; reuse as lp
#pragma unroll
  for (int mi = 0; mi < 4; ++mi)
#pragma unroll
    for (int ni = 0; ni < 4; ++ni)
#pragma unroll
      for (int r = 0; r < 4; ++r)
        lp[mi * 16 + lg * 4 + r][ni * 16 + lr] = f2b(s[mi][ni][r]);
  __syncthreads();

  // O = P @ V : A-frags from lp rows, B-frags from vt rows (both contiguous)
  f32x4 o[4][2];
#pragma unroll
  for (int i = 0; i < 4; ++i) { o[i][0] = z4; o[i][1] = z4; }
#pragma unroll
  for (int ks = 0; ks < 2; ++ks) {
    bf16x8 bv[2];
#pragma unroll
    for (int nd = 0; nd < 2; ++nd)
      bv[nd] = __builtin_bit_cast(bf16x8,
          *reinterpret_cast<const u16x8*>(&vt[nd * 16 + lr][ks * 32 + lg * 8]));
#pragma unroll
    for (int mi = 0; mi < 4; ++mi) {
      bf16x8 ap = __builtin_bit_cast(bf16x8,
          *reinterpret_cast<const u16x8*>(&lp[mi * 16 + lr][ks * 32 + lg * 8]));
#pragma unroll
      for (int nd = 0; nd < 2; ++nd)
        o[mi][nd] = __builtin_amdgcn_mfma_f32_16x16x32_bf16(ap, bv[nd],
                                                            o[mi][nd], 0, 0, 0);
    }
  }
#pragma unroll
  for (int mi = 0; mi < 4; ++mi)
#pragma unroll
    for (int r = 0; r < 4; ++r) {
      const int n = mi * 16 + lg * 4 + r;
      if (n < 49) {
        const float inv = rs[mi][r];
        u16* dst = y + ((size_t)b * 49 + n) * 384 + h * 32 + lr;
        dst[0] = f2b(o[mi][0][r] * inv);
        dst[16] = f2b(o[mi][1][r] * inv);
      }
    }
}

// ---------------- launcher ----------------
extern "C" void kernel_launch(void* const* d_in, const int* in_sizes, int n_in,
                              void* d_out, int out_size, void* d_ws,
                              size_t ws_size, hipStream_t stream) {
  (void)in_sizes; (void)n_in; (void)out_size; (void)ws_size;
  const float* x      = (const float*)d_in[0];
  const float* mask   = (const float*)d_in[1];
  const float* qkv_w  = (const float*)d_in[2];
  const float* qkv_b  = (const float*)d_in[3];
  const float* tau    = (const float*)d_in[4];
  const float* cpb_w1 = (const float*)d_in[5];
  const float* cpb_b1 = (const float*)d_in[6];
  const float* cpb_w2 = (const float*)d_in[7];
  const float* cpb_b2 = (const float*)d_in[8];
  const float* proj_w = (const float*)d_in[9];
  const float* proj_b = (const float*)d_in[10];
  float* out = (float*)d_out;

  char* ws = (char*)d_ws;
  u16* x_bf     = (u16*)(ws);
  u16* qkvw_bf  = (u16*)(ws + 77070336);
  u16* projw_bf = (u16*)(ws + 77955072);
  float* cpb_t  = (float*)(ws + 78249984);
  u16* qkv_bf   = (u16*)(ws + 78365696);
  u16* y_bf     = (u16*)(ws + 309576704);

  k_cast<<<dim3(18816), dim3(256), 0, stream>>>(x, x_bf, 4816896);
  k_cast<<<dim3(216), dim3(256), 0, stream>>>(qkv_w, qkvw_bf, 55296);
  k_cast<<<dim3(72), dim3(256), 0, stream>>>(proj_w, projw_bf, 18432);
  k_cpb<<<dim3(38), dim3(64), 0, stream>>>(cpb_w1, cpb_b1, cpb_w2, cpb_b2, cpb_t);

  // qkv = x @ qkv_w^T + qkv_b   (M=100352, N=1152, K=384)
  k_gemm_bt<false><<<dim3(784 * 9), dim3(256), 0, stream>>>(
      x_bf, qkvw_bf, qkv_b, qkv_bf, 100352, 1152, 384);

  k_attn<<<dim3(2048, 12), dim3(64), 0, stream>>>(qkv_bf, tau, cpb_t, mask, y_bf);

  // out = y @ proj_w^T + proj_b (M=100352, N=384, K=384)
  k_gemm_bt<true><<<dim3(784 * 3), dim3(256), 0, stream>>>(
      y_bf, projw_bf, proj_b, out, 100352, 384, 384);
}

// Round 2
// 431.835 us; speedup vs baseline: 1.3473x; 1.3473x over previous
//
#include <hip/hip_runtime.h>

// SwinV2 window attention, MI355X.
//   prep: cast weights+x -> bf16, CPB table, combined bias table comb[h][w][n][52]
//   k_gemm_bt<false>: qkv = x @ qkv_w^T + b   (bf16 MFMA, bf16 out)
//   k_attn: per (window,head); S^T = mfma(K,Q) -> in-register softmax (2 shfl)
//           -> P redistributed to PV B-frags via shfl/bpermute (no LDS round trip)
//   k_gemm_bt<true>:  out = y @ proj_w^T + b  (f32 out)
//
// Workspace layout (bytes):
//   0          x_bf      77,070,336
//   77070336   qkvw_bf      884,736
//   77955072   projw_bf     294,912
//   78249984   cpb_t        115,248 (pad to 115,712)
//   78365696   qkv_bf   231,211,008
//   309576704  y_bf      77,070,336
//   386647040  comb       7,827,456 (+64 guard)
//   total ~394.5 MB

typedef float f32x4 __attribute__((ext_vector_type(4)));
typedef __bf16 bf16x8 __attribute__((ext_vector_type(8)));
typedef unsigned short u16;
typedef u16 u16x8 __attribute__((ext_vector_type(8)));
typedef u16 u16x4 __attribute__((ext_vector_type(4)));
typedef unsigned u32x4 __attribute__((ext_vector_type(4)));

__device__ __forceinline__ float b2f(unsigned u) {
  return __builtin_bit_cast(float, u << 16);
}
__device__ __forceinline__ u16 f2b(float f) {  // RNE f32->bf16
  unsigned u = __builtin_bit_cast(unsigned, f);
  u += 0x7fffu + ((u >> 16) & 1u);
  return (u16)(u >> 16);
}
__device__ __forceinline__ unsigned pack2(float a, float b) {
  return (unsigned)f2b(a) | ((unsigned)f2b(b) << 16);
}

#define GLD16(gp, lp)                                        \
  __builtin_amdgcn_global_load_lds(                          \
      (const __attribute__((address_space(1))) void*)(gp),   \
      (__attribute__((address_space(3))) void*)(lp), 16, 0, 0)

// ---------------- cast f32 -> bf16, 8 elems/thread ----------------
__global__ __launch_bounds__(256) void k_cast(const float* __restrict__ in,
                                              u16* __restrict__ out, int n8) {
  int i = blockIdx.x * 256 + threadIdx.x;
  if (i >= n8) return;
  const float4* p = reinterpret_cast<const float4*>(in) + (size_t)i * 2;
  float4 a = p[0], b = p[1];
  u16x8 r;
  r[0] = f2b(a.x); r[1] = f2b(a.y); r[2] = f2b(a.z); r[3] = f2b(a.w);
  r[4] = f2b(b.x); r[5] = f2b(b.y); r[6] = f2b(b.z); r[7] = f2b(b.w);
  *(reinterpret_cast<u16x8*>(out) + i) = r;
}

// ---------------- CPB bias table: cpb_t[h][n][m] (unpadded 49) ----------------
__global__ __launch_bounds__(64) void k_cpb(const float* __restrict__ w1,
                                            const float* __restrict__ b1,
                                            const float* __restrict__ w2,
                                            const float* __restrict__ b2,
                                            float* __restrict__ cpb_t) {
  int p = blockIdx.x * 64 + threadIdx.x;
  if (p >= 49 * 49) return;
  int n = p / 49, m = p % 49;
  float d0 = (float)(n / 7 - m / 7);
  float d1 = (float)(n % 7 - m % 7);
  float a0 = log1pf(fabsf(d0)); a0 = (d0 < 0.f) ? -a0 : a0;
  float a1 = log1pf(fabsf(d1)); a1 = (d1 < 0.f) ? -a1 : a1;
  float acc[12];
#pragma unroll
  for (int h = 0; h < 12; ++h) acc[h] = b2[h];
  for (int j = 0; j < 64; ++j) {
    float hj = fmaxf(a0 * w1[2 * j] + a1 * w1[2 * j + 1] + b1[j], 0.f);
#pragma unroll
    for (int h = 0; h < 12; ++h) acc[h] += hj * w2[h * 64 + j];
  }
#pragma unroll
  for (int h = 0; h < 12; ++h) cpb_t[h * 2401 + p] = acc[h];
}

// ---------------- combined bias: comb[(h*64+w)*49+n][52] = cpb + mask --------
__global__ __launch_bounds__(256) void k_comb(const float* __restrict__ cpb_t,
                                              const float* __restrict__ mask,
                                              float* __restrict__ comb) {
  const int wh = blockIdx.x;  // h*64 + w
  const int h = wh >> 6, w = wh & 63;
  const float* c = cpb_t + h * 2401;
  const float* m = mask + (size_t)w * 2401;
  float* o = comb + (size_t)wh * 2548;
  for (int p = threadIdx.x; p < 2548; p += 256) {
    int n = p / 52, mc = p % 52;
    float v = (mc < 49) ? c[n * 49 + mc] + m[n * 49 + mc] : 0.f;
    o[p] = v;
  }
}

// ---------------- GEMM: C[M,N] = A[M,K] @ W[N,K]^T + bias ----------------
template <bool OUT_F32>
__global__ __launch_bounds__(256) void k_gemm_bt(
    const u16* __restrict__ A, const u16* __restrict__ W,
    const float* __restrict__ bias, void* __restrict__ Cv,
    int M, int N, int K) {
  (void)M;
  __shared__ __align__(16) u16 sA[2][4096];  // [128][32]
  __shared__ __align__(16) u16 sB[2][4096];
  const int tid = threadIdx.x;
  const int nt = N >> 7;
  const int m0 = (blockIdx.x / nt) << 7;
  const int n0 = (blockIdx.x % nt) << 7;
  const int srow = tid >> 2;
  const int scol = (tid & 3) << 3;
  const u16* ga0 = A + (size_t)(m0 + srow) * K + scol;
  const u16* ga1 = ga0 + (size_t)64 * K;
  const u16* gw0 = W + (size_t)(n0 + srow) * K + scol;
  const u16* gw1 = gw0 + (size_t)64 * K;
  const int KT = K >> 5;

#define STAGE(buf, kk)                              \
  do {                                              \
    GLD16(ga0 + (kk), &sA[buf][tid * 8]);           \
    GLD16(ga1 + (kk), &sA[buf][2048 + tid * 8]);    \
    GLD16(gw0 + (kk), &sB[buf][tid * 8]);           \
    GLD16(gw1 + (kk), &sB[buf][2048 + tid * 8]);    \
  } while (0)

  STAGE(0, 0);

  const f32x4 z4 = {0.f, 0.f, 0.f, 0.f};
  f32x4 acc[4][4];
#pragma unroll
  for (int i = 0; i < 4; ++i)
#pragma unroll
    for (int j = 0; j < 4; ++j) acc[i][j] = z4;

  const int l = tid & 63, w = tid >> 6;
  const int wm = (w >> 1) << 6, wn = (w & 1) << 6;
  const int lr = l & 15, lg = l >> 4;
  const int arow = wm + lr, brow = wn + lr;

  for (int t = 0; t < KT; ++t) {
    __syncthreads();
    if (t + 1 < KT) STAGE((t + 1) & 1, (t + 1) * 32);
    const u16* pa = sA[t & 1];
    const u16* pb = sB[t & 1];
    bf16x8 af[4], bfv[4];
#pragma unroll
    for (int mi = 0; mi < 4; ++mi)
      af[mi] = __builtin_bit_cast(bf16x8,
          *reinterpret_cast<const u16x8*>(pa + (arow + mi * 16) * 32 + lg * 8));
#pragma unroll
    for (int ni = 0; ni < 4; ++ni)
      bfv[ni] = __builtin_bit_cast(bf16x8,
          *reinterpret_cast<const u16x8*>(pb + (brow + ni * 16) * 32 + lg * 8));
#pragma unroll
    for (int mi = 0; mi < 4; ++mi)
#pragma unroll
      for (int ni = 0; ni < 4; ++ni)
        acc[mi][ni] = __builtin_amdgcn_mfma_f32_16x16x32_bf16(
            af[mi], bfv[ni], acc[mi][ni], 0, 0, 0);
  }
#undef STAGE

  float bv[4];
#pragma unroll
  for (int ni = 0; ni < 4; ++ni) bv[ni] = bias[n0 + wn + ni * 16 + lr];
#pragma unroll
  for (int mi = 0; mi < 4; ++mi)
#pragma unroll
    for (int r = 0; r < 4; ++r) {
      const size_t row = (size_t)(m0 + wm + mi * 16 + lg * 4 + r);
#pragma unroll
      for (int ni = 0; ni < 4; ++ni) {
        const int col = n0 + wn + ni * 16 + lr;
        float v = acc[mi][ni][r] + bv[ni];
        if (OUT_F32)
          reinterpret_cast<float*>(Cv)[row * N + col] = v;
        else
          reinterpret_cast<u16*>(Cv)[row * N + col] = f2b(v);
      }
    }
}

// ---------------- attention: one wave per (window b, head h) ----------------
// S^T = mfma(K,Q): lane owns col n=lr of S^T -> softmax = per-lane 16 + 2 shfl.
// P -> PV B-frags via pack2 + shfl (no LDS). V^T overlays K LDS region.
__global__ __launch_bounds__(64, 4) void k_attn(
    const u16* __restrict__ qkv, const float* __restrict__ tau,
    const float* __restrict__ comb, u16* __restrict__ y) {
  const int b = blockIdx.x, h = blockIdx.y;
  const int l = threadIdx.x;
  __shared__ __align__(16) u16 lk[64][40];  // 5120 B, overlaid by vt
  __shared__ __align__(16) u16 lq[64][40];  // 5120 B, live throughout
  u16(*vt)[72] = reinterpret_cast<u16(*)[72]>(&lk[0][0]);  // [32][72] = 4608 B

  const float tauh = fmaxf(tau[h], 0.01f);
  const bool valid = l < 49;
  u16x8 v8s[4];
  {
    const u16* base = qkv + ((size_t)b * 49 + (valid ? l : 0)) * 1152 + h * 32;
    float qv[32], kv[32];
#pragma unroll
    for (int c = 0; c < 4; ++c) {
      u16x8 q8 = {0, 0, 0, 0, 0, 0, 0, 0};
      u16x8 k8 = {0, 0, 0, 0, 0, 0, 0, 0};
      u16x8 v8 = {0, 0, 0, 0, 0, 0, 0, 0};
      if (valid) {
        q8 = *reinterpret_cast<const u16x8*>(base + c * 8);
        k8 = *reinterpret_cast<const u16x8*>(base + 384 + c * 8);
        v8 = *reinterpret_cast<const u16x8*>(base + 768 + c * 8);
      }
      v8s[c] = v8;
#pragma unroll
      for (int e = 0; e < 8; ++e) {
        qv[c * 8 + e] = b2f((unsigned)q8[e]);
        kv[c * 8 + e] = b2f((unsigned)k8[e]);
      }
    }
    float sq = 0.f, sk = 0.f;
#pragma unroll
    for (int j = 0; j < 32; ++j) { sq += qv[j] * qv[j]; sk += kv[j] * kv[j]; }
    const float qs = (1.f / fmaxf(sqrtf(sq), 1e-12f)) / tauh;  // fold 1/tau
    const float ks = 1.f / fmaxf(sqrtf(sk), 1e-12f);
#pragma unroll
    for (int c = 0; c < 4; ++c) {
      u16x8 wq, wk;
#pragma unroll
      for (int e = 0; e < 8; ++e) {
        wq[e] = f2b(qv[c * 8 + e] * qs);
        wk[e] = f2b(kv[c * 8 + e] * ks);
      }
      *reinterpret_cast<u16x8*>(&lq[l][c * 8]) = wq;
      *reinterpret_cast<u16x8*>(&lk[l][c * 8]) = wk;
    }
  }
  __syncthreads();

  const int lr = l & 15, lg = l >> 4;
  bf16x8 kf[4];
#pragma unroll
  for (int mi = 0; mi < 4; ++mi)
    kf[mi] = __builtin_bit_cast(bf16x8,
        *reinterpret_cast<const u16x8*>(&lk[mi * 16 + lr][lg * 8]));
  __syncthreads();  // lk dead -> overlay vt
#pragma unroll
  for (int c = 0; c < 4; ++c)
#pragma unroll
    for (int e = 0; e < 8; ++e) vt[c * 8 + e][l] = v8s[c][e];
  __syncthreads();
  bf16x8 vtf[2][2];
#pragma unroll
  for (int dd = 0; dd < 2; ++dd)
#pragma unroll
    for (int ks = 0; ks < 2; ++ks)
      vtf[dd][ks] = __builtin_bit_cast(bf16x8,
          *reinterpret_cast<const u16x8*>(&vt[dd * 16 + lr][ks * 32 + lg * 8]));

  const f32x4 z4 = {0.f, 0.f, 0.f, 0.f};
  const int src0 = lr + 16 * ((2 * lg) & 3);
  const int src1 = lr + 16 * ((2 * lg + 1) & 3);
  const bool hi5 = lg >= 2;
  const float* bbase = comb + (size_t)(h * 64 + (b & 63)) * 2548;

#pragma unroll
  for (int nj = 0; nj < 4; ++nj) {
    const bf16x8 qf = __builtin_bit_cast(bf16x8,
        *reinterpret_cast<const u16x8*>(&lq[nj * 16 + lr][lg * 8]));
    f32x4 s[4];
#pragma unroll
    for (int mi = 0; mi < 4; ++mi)
      s[mi] = __builtin_amdgcn_mfma_f32_16x16x32_bf16(kf[mi], qf, z4, 0, 0, 0);

    const int n = nj * 16 + lr;
    const float* bp = bbase + (size_t)(n < 49 ? n : 48) * 52 + lg * 4;
    f32x4 bia[4];
#pragma unroll
    for (int mi = 0; mi < 4; ++mi)
      bia[mi] = *reinterpret_cast<const f32x4*>(bp + mi * 16);

    float v[4][4];
#pragma unroll
    for (int mi = 0; mi < 3; ++mi)  // m = mi*16+lg*4+r <= 47 < 49: all valid
#pragma unroll
      for (int r = 0; r < 4; ++r) v[mi][r] = s[mi][r] + bia[mi][r];
#pragma unroll
    for (int r = 0; r < 4; ++r) {  // mi=3: only m=48 (lg==0, r==0) valid
      float t = s[3][r] + bia[3][r];
      v[3][r] = (lg == 0 && r == 0) ? t : -1e30f;
    }

    float mx = v[0][0];
#pragma unroll
    for (int mi = 0; mi < 4; ++mi)
#pragma unroll
      for (int r = 0; r < 4; ++r) mx = fmaxf(mx, v[mi][r]);
    mx = fmaxf(mx, __shfl_xor(mx, 16));
    mx = fmaxf(mx, __shfl_xor(mx, 32));
    float sum = 0.f;
#pragma unroll
    for (int mi = 0; mi < 4; ++mi)
#pragma unroll
      for (int r = 0; r < 4; ++r) {
        v[mi][r] = __expf(v[mi][r] - mx);
        sum += v[mi][r];
      }
    sum += __shfl_xor(sum, 16);
    sum += __shfl_xor(sum, 32);
    const float rinv = __builtin_amdgcn_rcpf(sum);

    unsigned pk[4][2];
#pragma unroll
    for (int mi = 0; mi < 4; ++mi) {
      pk[mi][0] = pack2(v[mi][0] * rinv, v[mi][1] * rinv);
      pk[mi][1] = pack2(v[mi][2] * rinv, v[mi][3] * rinv);
    }
    // redistribute: pf[ks] elem e = P^T[ks*32+lg*8+e][n]
    bf16x8 pf[2];
#pragma unroll
    for (int ks = 0; ks < 2; ++ks) {
      unsigned a0 = (unsigned)__shfl((int)pk[2 * ks][0], src0);
      unsigned b0 = (unsigned)__shfl((int)pk[2 * ks + 1][0], src0);
      unsigned a1 = (unsigned)__shfl((int)pk[2 * ks][1], src0);
      unsigned b1 = (unsigned)__shfl((int)pk[2 * ks + 1][1], src0);
      unsigned a2 = (unsigned)__shfl((int)pk[2 * ks][0], src1);
      unsigned b2_ = (unsigned)__shfl((int)pk[2 * ks + 1][0], src1);
      unsigned a3 = (unsigned)__shfl((int)pk[2 * ks][1], src1);
      unsigned b3 = (unsigned)__shfl((int)pk[2 * ks + 1][1], src1);
      u32x4 ww = {hi5 ? b0 : a0, hi5 ? b1 : a1, hi5 ? b2_ : a2, hi5 ? b3 : a3};
      pf[ks] = __builtin_bit_cast(bf16x8, ww);
    }

    f32x4 o0 = __builtin_amdgcn_mfma_f32_16x16x32_bf16(vtf[0][0], pf[0], z4, 0, 0, 0);
    o0 = __builtin_amdgcn_mfma_f32_16x16x32_bf16(vtf[0][1], pf[1], o0, 0, 0, 0);
    f32x4 o1 = __builtin_amdgcn_mfma_f32_16x16x32_bf16(vtf[1][0], pf[0], z4, 0, 0, 0);
    o1 = __builtin_amdgcn_mfma_f32_16x16x32_bf16(vtf[1][1], pf[1], o1, 0, 0, 0);

    if (n < 49) {
      u16* dst = y + ((size_t)b * 49 + n) * 384 + h * 32 + lg * 4;
      u16x4 w0 = {f2b(o0[0]), f2b(o0[1]), f2b(o0[2]), f2b(o0[3])};
      u16x4 w1 = {f2b(o1[0]), f2b(o1[1]), f2b(o1[2]), f2b(o1[3])};
      *reinterpret_cast<u16x4*>(dst) = w0;
      *reinterpret_cast<u16x4*>(dst + 16) = w1;
    }
  }
}

// ---------------- launcher ----------------
extern "C" void kernel_launch(void* const* d_in, const int* in_sizes, int n_in,
                              void* d_out, int out_size, void* d_ws,
                              size_t ws_size, hipStream_t stream) {
  (void)in_sizes; (void)n_in; (void)out_size; (void)ws_size;
  const float* x      = (const float*)d_in[0];
  const float* mask   = (const float*)d_in[1];
  const float* qkv_w  = (const float*)d_in[2];
  const float* qkv_b  = (const float*)d_in[3];
  const float* tau    = (const float*)d_in[4];
  const float* cpb_w1 = (const float*)d_in[5];
  const float* cpb_b1 = (const float*)d_in[6];
  const float* cpb_w2 = (const float*)d_in[7];
  const float* cpb_b2 = (const float*)d_in[8];
  const float* proj_w = (const float*)d_in[9];
  const float* proj_b = (const float*)d_in[10];
  float* out = (float*)d_out;

  char* ws = (char*)d_ws;
  u16* x_bf     = (u16*)(ws);
  u16* qkvw_bf  = (u16*)(ws + 77070336);
  u16* projw_bf = (u16*)(ws + 77955072);
  float* cpb_t  = (float*)(ws + 78249984);
  u16* qkv_bf   = (u16*)(ws + 78365696);
  u16* y_bf     = (u16*)(ws + 309576704);
  float* comb   = (float*)(ws + 386647040);

  k_cast<<<dim3(18816), dim3(256), 0, stream>>>(x, x_bf, 4816896);
  k_cast<<<dim3(216), dim3(256), 0, stream>>>(qkv_w, qkvw_bf, 55296);
  k_cast<<<dim3(72), dim3(256), 0, stream>>>(proj_w, projw_bf, 18432);
  k_cpb<<<dim3(38), dim3(64), 0, stream>>>(cpb_w1, cpb_b1, cpb_w2, cpb_b2, cpb_t);
  k_comb<<<dim3(768), dim3(256), 0, stream>>>(cpb_t, mask, comb);

  // qkv = x @ qkv_w^T + qkv_b   (M=100352, N=1152, K=384)
  k_gemm_bt<false><<<dim3(784 * 9), dim3(256), 0, stream>>>(
      x_bf, qkvw_bf, qkv_b, qkv_bf, 100352, 1152, 384);

  k_attn<<<dim3(2048, 12), dim3(64), 0, stream>>>(qkv_bf, tau, comb, y_bf);

  // out = y @ proj_w^T + proj_b (M=100352, N=384, K=384)
  k_gemm_bt<true><<<dim3(784 * 3), dim3(256), 0, stream>>>(
      y_bf, projw_bf, proj_b, out, 100352, 384, 384);
}

// Round 3
// 423.546 us; speedup vs baseline: 1.3737x; 1.0196x over previous
//
#include <hip/hip_runtime.h>

// SwinV2 window attention, MI355X.
//   prep: cast weights+x -> bf16, CPB table, combined bias table comb[h][w][n][52]
//   k_gemm_bt<false>: qkv = x @ qkv_w^T + b   (bf16 MFMA, bf16 out)
//   k_attn: per (window,head); S^T = mfma(K,Q) -> in-register softmax
//           -> P redistributed to PV B-frags via shfl (no LDS round trip)
//   k_gemm_bt<true>:  out = y @ proj_w^T + b  (f32 out)
// R3: GEMM LDS XOR-swizzle (pre-swizzled global src + swizzled ds_read;
//     8-way -> 2-way bank conflicts) + XCD-aware block swizzle (A-panel L2 reuse).
//
// Workspace layout (bytes):
//   0          x_bf      77,070,336
//   77070336   qkvw_bf      884,736
//   77955072   projw_bf     294,912
//   78249984   cpb_t        115,248 (pad to 115,712)
//   78365696   qkv_bf   231,211,008
//   309576704  y_bf      77,070,336
//   386647040  comb       7,827,456
//   total ~394.5 MB

typedef float f32x4 __attribute__((ext_vector_type(4)));
typedef __bf16 bf16x8 __attribute__((ext_vector_type(8)));
typedef unsigned short u16;
typedef u16 u16x8 __attribute__((ext_vector_type(8)));
typedef u16 u16x4 __attribute__((ext_vector_type(4)));
typedef unsigned u32x4 __attribute__((ext_vector_type(4)));

__device__ __forceinline__ float b2f(unsigned u) {
  return __builtin_bit_cast(float, u << 16);
}
__device__ __forceinline__ u16 f2b(float f) {  // RNE f32->bf16
  unsigned u = __builtin_bit_cast(unsigned, f);
  u += 0x7fffu + ((u >> 16) & 1u);
  return (u16)(u >> 16);
}
__device__ __forceinline__ unsigned pack2(float a, float b) {
  return (unsigned)f2b(a) | ((unsigned)f2b(b) << 16);
}

#define GLD16(gp, lp)                                        \
  __builtin_amdgcn_global_load_lds(                          \
      (const __attribute__((address_space(1))) void*)(gp),   \
      (__attribute__((address_space(3))) void*)(lp), 16, 0, 0)

// ---------------- cast f32 -> bf16, 8 elems/thread ----------------
__global__ __launch_bounds__(256) void k_cast(const float* __restrict__ in,
                                              u16* __restrict__ out, int n8) {
  int i = blockIdx.x * 256 + threadIdx.x;
  if (i >= n8) return;
  const float4* p = reinterpret_cast<const float4*>(in) + (size_t)i * 2;
  float4 a = p[0], b = p[1];
  u16x8 r;
  r[0] = f2b(a.x); r[1] = f2b(a.y); r[2] = f2b(a.z); r[3] = f2b(a.w);
  r[4] = f2b(b.x); r[5] = f2b(b.y); r[6] = f2b(b.z); r[7] = f2b(b.w);
  *(reinterpret_cast<u16x8*>(out) + i) = r;
}

// ---------------- CPB bias table: cpb_t[h][n][m] (unpadded 49) ----------------
__global__ __launch_bounds__(64) void k_cpb(const float* __restrict__ w1,
                                            const float* __restrict__ b1,
                                            const float* __restrict__ w2,
                                            const float* __restrict__ b2,
                                            float* __restrict__ cpb_t) {
  int p = blockIdx.x * 64 + threadIdx.x;
  if (p >= 49 * 49) return;
  int n = p / 49, m = p % 49;
  float d0 = (float)(n / 7 - m / 7);
  float d1 = (float)(n % 7 - m % 7);
  float a0 = log1pf(fabsf(d0)); a0 = (d0 < 0.f) ? -a0 : a0;
  float a1 = log1pf(fabsf(d1)); a1 = (d1 < 0.f) ? -a1 : a1;
  float acc[12];
#pragma unroll
  for (int h = 0; h < 12; ++h) acc[h] = b2[h];
  for (int j = 0; j < 64; ++j) {
    float hj = fmaxf(a0 * w1[2 * j] + a1 * w1[2 * j + 1] + b1[j], 0.f);
#pragma unroll
    for (int h = 0; h < 12; ++h) acc[h] += hj * w2[h * 64 + j];
  }
#pragma unroll
  for (int h = 0; h < 12; ++h) cpb_t[h * 2401 + p] = acc[h];
}

// ---------------- combined bias: comb[(h*64+w)*49+n][52] = cpb + mask --------
__global__ __launch_bounds__(256) void k_comb(const float* __restrict__ cpb_t,
                                              const float* __restrict__ mask,
                                              float* __restrict__ comb) {
  const int wh = blockIdx.x;  // h*64 + w
  const int h = wh >> 6, w = wh & 63;
  const float* c = cpb_t + h * 2401;
  const float* m = mask + (size_t)w * 2401;
  float* o = comb + (size_t)wh * 2548;
  for (int p = threadIdx.x; p < 2548; p += 256) {
    int n = p / 52, mc = p % 52;
    float v = (mc < 49) ? c[n * 49 + mc] + m[n * 49 + mc] : 0.f;
    o[p] = v;
  }
}

// ---------------- GEMM: C[M,N] = A[M,K] @ W[N,K]^T + bias ----------------
// 128x128 tile, BK=32, 4 waves (2x2). LDS via global_load_lds w16, dbuf.
// LDS layout XOR-swizzled: LDS[row][cg] holds global col-group cg^((row>>1)&3)
// (swizzle applied on the per-lane GLOBAL source address; ds_read applies the
// same XOR -> 2-way bank conflicts only). XCD-swizzled blockIdx.
template <bool OUT_F32>
__global__ __launch_bounds__(256) void k_gemm_bt(
    const u16* __restrict__ A, const u16* __restrict__ W,
    const float* __restrict__ bias, void* __restrict__ Cv,
    int M, int N, int K) {
  (void)M;
  __shared__ __align__(16) u16 sA[2][4096];  // [128][32]
  __shared__ __align__(16) u16 sB[2][4096];
  const int tid = threadIdx.x;
  // XCD-aware bijective remap (grid divisible by 8)
  const int cpx = (int)(gridDim.x >> 3);
  int bid = (int)blockIdx.x;
  bid = (bid & 7) * cpx + (bid >> 3);
  const int nt = N >> 7;
  const int m0 = (bid / nt) << 7;
  const int n0 = (bid % nt) << 7;
  const int srow = tid >> 2;                               // 0..63
  const int scs = (((tid & 3) ^ ((srow >> 1) & 3)) << 3);  // swizzled col grp
  const u16* ga0 = A + (size_t)(m0 + srow) * K + scs;
  const u16* ga1 = ga0 + (size_t)64 * K;
  const u16* gw0 = W + (size_t)(n0 + srow) * K + scs;
  const u16* gw1 = gw0 + (size_t)64 * K;
  const int KT = K >> 5;

#define STAGE(buf, kk)                              \
  do {                                              \
    GLD16(ga0 + (kk), &sA[buf][tid * 8]);           \
    GLD16(ga1 + (kk), &sA[buf][2048 + tid * 8]);    \
    GLD16(gw0 + (kk), &sB[buf][tid * 8]);           \
    GLD16(gw1 + (kk), &sB[buf][2048 + tid * 8]);    \
  } while (0)

  STAGE(0, 0);

  const f32x4 z4 = {0.f, 0.f, 0.f, 0.f};
  f32x4 acc[4][4];
#pragma unroll
  for (int i = 0; i < 4; ++i)
#pragma unroll
    for (int j = 0; j < 4; ++j) acc[i][j] = z4;

  const int l = tid & 63, w = tid >> 6;
  const int wm = (w >> 1) << 6, wn = (w & 1) << 6;
  const int lr = l & 15, lg = l >> 4;
  const int arow = wm + lr, brow = wn + lr;
  const int cg = ((lg ^ ((lr >> 1) & 3)) << 3);  // swizzled read col offset

  for (int t = 0; t < KT; ++t) {
    __syncthreads();  // drains vmcnt: tile t resident in sA/sB[t&1]
    if (t + 1 < KT) STAGE((t + 1) & 1, (t + 1) * 32);
    const u16* pa = sA[t & 1];
    const u16* pb = sB[t & 1];
    bf16x8 af[4], bfv[4];
#pragma unroll
    for (int mi = 0; mi < 4; ++mi)
      af[mi] = __builtin_bit_cast(bf16x8,
          *reinterpret_cast<const u16x8*>(pa + (arow + mi * 16) * 32 + cg));
#pragma unroll
    for (int ni = 0; ni < 4; ++ni)
      bfv[ni] = __builtin_bit_cast(bf16x8,
          *reinterpret_cast<const u16x8*>(pb + (brow + ni * 16) * 32 + cg));
#pragma unroll
    for (int mi = 0; mi < 4; ++mi)
#pragma unroll
      for (int ni = 0; ni < 4; ++ni)
        acc[mi][ni] = __builtin_amdgcn_mfma_f32_16x16x32_bf16(
            af[mi], bfv[ni], acc[mi][ni], 0, 0, 0);
  }
#undef STAGE

  float bv[4];
#pragma unroll
  for (int ni = 0; ni < 4; ++ni) bv[ni] = bias[n0 + wn + ni * 16 + lr];
#pragma unroll
  for (int mi = 0; mi < 4; ++mi)
#pragma unroll
    for (int r = 0; r < 4; ++r) {
      const size_t row = (size_t)(m0 + wm + mi * 16 + lg * 4 + r);
#pragma unroll
      for (int ni = 0; ni < 4; ++ni) {
        const int col = n0 + wn + ni * 16 + lr;
        float v = acc[mi][ni][r] + bv[ni];
        if (OUT_F32)
          reinterpret_cast<float*>(Cv)[row * N + col] = v;
        else
          reinterpret_cast<u16*>(Cv)[row * N + col] = f2b(v);
      }
    }
}

// ---------------- attention: one wave per (window b, head h) ----------------
__global__ __launch_bounds__(64, 4) void k_attn(
    const u16* __restrict__ qkv, const float* __restrict__ tau,
    const float* __restrict__ comb, u16* __restrict__ y) {
  const int b = blockIdx.x, h = blockIdx.y;
  const int l = threadIdx.x;
  __shared__ __align__(16) u16 lk[64][40];  // 5120 B, overlaid by vt
  __shared__ __align__(16) u16 lq[64][40];  // 5120 B, live throughout
  u16(*vt)[72] = reinterpret_cast<u16(*)[72]>(&lk[0][0]);  // [32][72] = 4608 B

  const float tauh = fmaxf(tau[h], 0.01f);
  const bool valid = l < 49;
  u16x8 v8s[4];
  {
    const u16* base = qkv + ((size_t)b * 49 + (valid ? l : 0)) * 1152 + h * 32;
    float qv[32], kv[32];
#pragma unroll
    for (int c = 0; c < 4; ++c) {
      u16x8 q8 = {0, 0, 0, 0, 0, 0, 0, 0};
      u16x8 k8 = {0, 0, 0, 0, 0, 0, 0, 0};
      u16x8 v8 = {0, 0, 0, 0, 0, 0, 0, 0};
      if (valid) {
        q8 = *reinterpret_cast<const u16x8*>(base + c * 8);
        k8 = *reinterpret_cast<const u16x8*>(base + 384 + c * 8);
        v8 = *reinterpret_cast<const u16x8*>(base + 768 + c * 8);
      }
      v8s[c] = v8;
#pragma unroll
      for (int e = 0; e < 8; ++e) {
        qv[c * 8 + e] = b2f((unsigned)q8[e]);
        kv[c * 8 + e] = b2f((unsigned)k8[e]);
      }
    }
    float sq = 0.f, sk = 0.f;
#pragma unroll
    for (int j = 0; j < 32; ++j) { sq += qv[j] * qv[j]; sk += kv[j] * kv[j]; }
    const float qs = (1.f / fmaxf(sqrtf(sq), 1e-12f)) / tauh;  // fold 1/tau
    const float ks = 1.f / fmaxf(sqrtf(sk), 1e-12f);
#pragma unroll
    for (int c = 0; c < 4; ++c) {
      u16x8 wq, wk;
#pragma unroll
      for (int e = 0; e < 8; ++e) {
        wq[e] = f2b(qv[c * 8 + e] * qs);
        wk[e] = f2b(kv[c * 8 + e] * ks);
      }
      *reinterpret_cast<u16x8*>(&lq[l][c * 8]) = wq;
      *reinterpret_cast<u16x8*>(&lk[l][c * 8]) = wk;
    }
  }
  __syncthreads();

  const int lr = l & 15, lg = l >> 4;
  bf16x8 kf[4];
#pragma unroll
  for (int mi = 0; mi < 4; ++mi)
    kf[mi] = __builtin_bit_cast(bf16x8,
        *reinterpret_cast<const u16x8*>(&lk[mi * 16 + lr][lg * 8]));
  __syncthreads();  // lk dead -> overlay vt
#pragma unroll
  for (int c = 0; c < 4; ++c)
#pragma unroll
    for (int e = 0; e < 8; ++e) vt[c * 8 + e][l] = v8s[c][e];
  __syncthreads();
  bf16x8 vtf[2][2];
#pragma unroll
  for (int dd = 0; dd < 2; ++dd)
#pragma unroll
    for (int ks = 0; ks < 2; ++ks)
      vtf[dd][ks] = __builtin_bit_cast(bf16x8,
          *reinterpret_cast<const u16x8*>(&vt[dd * 16 + lr][ks * 32 + lg * 8]));

  const f32x4 z4 = {0.f, 0.f, 0.f, 0.f};
  const int src0 = lr + 16 * ((2 * lg) & 3);
  const int src1 = lr + 16 * ((2 * lg + 1) & 3);
  const bool hi5 = lg >= 2;
  const float* bbase = comb + (size_t)(h * 64 + (b & 63)) * 2548;

#pragma unroll
  for (int nj = 0; nj < 4; ++nj) {
    const bf16x8 qf = __builtin_bit_cast(bf16x8,
        *reinterpret_cast<const u16x8*>(&lq[nj * 16 + lr][lg * 8]));
    f32x4 s[4];
#pragma unroll
    for (int mi = 0; mi < 4; ++mi)
      s[mi] = __builtin_amdgcn_mfma_f32_16x16x32_bf16(kf[mi], qf, z4, 0, 0, 0);

    const int n = nj * 16 + lr;
    const float* bp = bbase + (size_t)(n < 49 ? n : 48) * 52 + lg * 4;
    f32x4 bia[4];
#pragma unroll
    for (int mi = 0; mi < 4; ++mi)
      bia[mi] = *reinterpret_cast<const f32x4*>(bp + mi * 16);

    float v[4][4];
#pragma unroll
    for (int mi = 0; mi < 3; ++mi)  // m <= 47: all valid
#pragma unroll
      for (int r = 0; r < 4; ++r) v[mi][r] = s[mi][r] + bia[mi][r];
#pragma unroll
    for (int r = 0; r < 4; ++r) {  // mi=3: only m=48 (lg==0, r==0) valid
      float t = s[3][r] + bia[3][r];
      v[3][r] = (lg == 0 && r == 0) ? t : -1e30f;
    }

    float mx = v[0][0];
#pragma unroll
    for (int mi = 0; mi < 4; ++mi)
#pragma unroll
      for (int r = 0; r < 4; ++r) mx = fmaxf(mx, v[mi][r]);
    mx = fmaxf(mx, __shfl_xor(mx, 16));
    mx = fmaxf(mx, __shfl_xor(mx, 32));
    float sum = 0.f;
#pragma unroll
    for (int mi = 0; mi < 4; ++mi)
#pragma unroll
      for (int r = 0; r < 4; ++r) {
        v[mi][r] = __expf(v[mi][r] - mx);
        sum += v[mi][r];
      }
    sum += __shfl_xor(sum, 16);
    sum += __shfl_xor(sum, 32);
    const float rinv = __builtin_amdgcn_rcpf(sum);

    unsigned pk[4][2];
#pragma unroll
    for (int mi = 0; mi < 4; ++mi) {
      pk[mi][0] = pack2(v[mi][0] * rinv, v[mi][1] * rinv);
      pk[mi][1] = pack2(v[mi][2] * rinv, v[mi][3] * rinv);
    }
    // redistribute: pf[ks] elem e = P^T[ks*32+lg*8+e][n]
    bf16x8 pf[2];
#pragma unroll
    for (int ks = 0; ks < 2; ++ks) {
      unsigned a0 = (unsigned)__shfl((int)pk[2 * ks][0], src0);
      unsigned b0 = (unsigned)__shfl((int)pk[2 * ks + 1][0], src0);
      unsigned a1 = (unsigned)__shfl((int)pk[2 * ks][1], src0);
      unsigned b1 = (unsigned)__shfl((int)pk[2 * ks + 1][1], src0);
      unsigned a2 = (unsigned)__shfl((int)pk[2 * ks][0], src1);
      unsigned b2_ = (unsigned)__shfl((int)pk[2 * ks + 1][0], src1);
      unsigned a3 = (unsigned)__shfl((int)pk[2 * ks][1], src1);
      unsigned b3 = (unsigned)__shfl((int)pk[2 * ks + 1][1], src1);
      u32x4 ww = {hi5 ? b0 : a0, hi5 ? b1 : a1, hi5 ? b2_ : a2, hi5 ? b3 : a3};
      pf[ks] = __builtin_bit_cast(bf16x8, ww);
    }

    f32x4 o0 = __builtin_amdgcn_mfma_f32_16x16x32_bf16(vtf[0][0], pf[0], z4, 0, 0, 0);
    o0 = __builtin_amdgcn_mfma_f32_16x16x32_bf16(vtf[0][1], pf[1], o0, 0, 0, 0);
    f32x4 o1 = __builtin_amdgcn_mfma_f32_16x16x32_bf16(vtf[1][0], pf[0], z4, 0, 0, 0);
    o1 = __builtin_amdgcn_mfma_f32_16x16x32_bf16(vtf[1][1], pf[1], o1, 0, 0, 0);

    if (n < 49) {
      u16* dst = y + ((size_t)b * 49 + n) * 384 + h * 32 + lg * 4;
      u16x4 w0 = {f2b(o0[0]), f2b(o0[1]), f2b(o0[2]), f2b(o0[3])};
      u16x4 w1 = {f2b(o1[0]), f2b(o1[1]), f2b(o1[2]), f2b(o1[3])};
      *reinterpret_cast<u16x4*>(dst) = w0;
      *reinterpret_cast<u16x4*>(dst + 16) = w1;
    }
  }
}

// ---------------- launcher ----------------
extern "C" void kernel_launch(void* const* d_in, const int* in_sizes, int n_in,
                              void* d_out, int out_size, void* d_ws,
                              size_t ws_size, hipStream_t stream) {
  (void)in_sizes; (void)n_in; (void)out_size; (void)ws_size;
  const float* x      = (const float*)d_in[0];
  const float* mask   = (const float*)d_in[1];
  const float* qkv_w  = (const float*)d_in[2];
  const float* qkv_b  = (const float*)d_in[3];
  const float* tau    = (const float*)d_in[4];
  const float* cpb_w1 = (const float*)d_in[5];
  const float* cpb_b1 = (const float*)d_in[6];
  const float* cpb_w2 = (const float*)d_in[7];
  const float* cpb_b2 = (const float*)d_in[8];
  const float* proj_w = (const float*)d_in[9];
  const float* proj_b = (const float*)d_in[10];
  float* out = (float*)d_out;

  char* ws = (char*)d_ws;
  u16* x_bf     = (u16*)(ws);
  u16* qkvw_bf  = (u16*)(ws + 77070336);
  u16* projw_bf = (u16*)(ws + 77955072);
  float* cpb_t  = (float*)(ws + 78249984);
  u16* qkv_bf   = (u16*)(ws + 78365696);
  u16* y_bf     = (u16*)(ws + 309576704);
  float* comb   = (float*)(ws + 386647040);

  k_cast<<<dim3(18816), dim3(256), 0, stream>>>(x, x_bf, 4816896);
  k_cast<<<dim3(216), dim3(256), 0, stream>>>(qkv_w, qkvw_bf, 55296);
  k_cast<<<dim3(72), dim3(256), 0, stream>>>(proj_w, projw_bf, 18432);
  k_cpb<<<dim3(38), dim3(64), 0, stream>>>(cpb_w1, cpb_b1, cpb_w2, cpb_b2, cpb_t);
  k_comb<<<dim3(768), dim3(256), 0, stream>>>(cpb_t, mask, comb);

  // qkv = x @ qkv_w^T + qkv_b   (M=100352, N=1152, K=384)
  k_gemm_bt<false><<<dim3(784 * 9), dim3(256), 0, stream>>>(
      x_bf, qkvw_bf, qkv_b, qkv_bf, 100352, 1152, 384);

  k_attn<<<dim3(2048, 12), dim3(64), 0, stream>>>(qkv_bf, tau, comb, y_bf);

  // out = y @ proj_w^T + proj_b (M=100352, N=384, K=384)
  k_gemm_bt<true><<<dim3(784 * 3), dim3(256), 0, stream>>>(
      y_bf, projw_bf, proj_b, out, 100352, 384, 384);
}